// Round 13
// baseline (200.331 us; speedup 1.0000x reference)
//
#include <hip/hip_runtime.h>
#include <stdint.h>

// DynamicSparseLinearAttention on MI355X.
// N=4, L=8192, H=8, D=V=128. Layout [n][l][h][d], row stride H*D = 1024 floats.
//
// Lessons: (R4) atomics write through L2 -> never. (R5) small grids starve the
// chip. (R6) per-lane strided 16B loads thrash L2; LDS staging with coalesced
// reads is mandatory. (R8) scalar LDS transpose reads cap at 2.4TB/s -> stage
// transposed+bf16-packed, frag reads = ds_read_b128. (R9-R12) pipelining and
// occupancy knobs are NULL: every kernel with the h-blocked 512B-segment
// pattern runs at ~4.0-4.4 TB/s demand rate (retile2 pure-copy = kv_vh fused =
// attn_out). The lever is DEMAND BYTES, not rate: read K once (no vh split),
// bf16 partials so CH=32 costs no extra merge traffic.
//
// 3 launches:
//  kv_direct: fused retile+GEMM. Grid (CH=32,8,4)=1024 blocks x 512 thr
//             (8 waves = 2 wr(d64) x 4 wc(v32)) -> 4 blocks/CU, 100% thread
//             occupancy, 8 steps. Per 32-s step: stage K(featmap)/V bf16-packed
//             transposed into LDS (b64 writes, b128 frag reads, XOR swizzle),
//             1-step register prefetch, lgkm-only barriers. bf16 partials
//             (write-once, no atomics; error ~8e-6 << 8.4e-4 threshold).
//             Ksum via ones-MFMA on wc==0 waves, fp32.
//  kv_merge:  sum CH bf16 partials in fp32 -> kvb bf16 [nh][v][d] + ksumg.
//  attn_out:  Q staged to LDS bf16 (row*17 padded chunks), score during staging
//             (fp32 + shfl_xor), B-frags direct from L2-hot kvb. One barrier.

#define LSEQ 8192
#define NHD  1024   // H*D
#define SP   20     // LDS dwords per d-row: 16 s-pair slots + 4 pad

typedef __attribute__((ext_vector_type(4))) float f32x4;
typedef __attribute__((ext_vector_type(8))) short bf16x8;
typedef unsigned short ushort_t;

static __device__ __forceinline__ unsigned short f2bf(float x) {
  union { float f; uint32_t u; } v; v.f = x;
  uint32_t r = v.u + 0x7FFFu + ((v.u >> 16) & 1u);  // RNE
  return (unsigned short)(r >> 16);
}
static __device__ __forceinline__ uint32_t pack_bf(float a, float b) {
  return (uint32_t)f2bf(a) | ((uint32_t)f2bf(b) << 16);
}
static __device__ __forceinline__ float featmap(float x) {
  // elu(x)+1 = x+1 (x>0) else exp(x)
  return x > 0.f ? x + 1.f : __expf(x);
}

// LDS-only barrier (ds ops drained; global loads stay in flight).
#define BAR_LGKM() asm volatile("s_waitcnt lgkmcnt(0)\n\ts_barrier" ::: "memory")

// ---------------- Phase 1: fused retile + KV GEMM ----------------
// Grid (CH, 8 h, 4 n), 512 thr = 8 waves = 2 wr(d64) x 4 wc(v32).
__global__ __launch_bounds__(512, 4) void kv_direct(const float* __restrict__ keys,
                                                    const float* __restrict__ values,
                                                    ushort_t* __restrict__ kvpb,
                                                    float* __restrict__ kspart) {
  __shared__ uint32_t kls[128 * SP];
  __shared__ uint32_t vls[128 * SP];
  const int tid = threadIdx.x;
  const int chunk = blockIdx.x, CH = gridDim.x;
  const int h = blockIdx.y, n = blockIdx.z, nh = n * 8 + h;
  const int lane = tid & 63, w = tid >> 6;
  const int wr = w >> 2, wc = w & 3;
  const int lr = lane & 15, lg = lane >> 4;
  const int sPer = LSEQ / CH;        // 256 at CH=32
  const int steps = sPer / 32;       // 8 at CH=32

  const size_t gb = ((size_t)n * LSEQ + (size_t)chunk * sPer) * NHD + h * 128;
  const float* gk = keys + gb;
  const float* gv = values + gb;

  // staging: wave w owns s = 4w..4w+3; lane a owns d-pair (2a, 2a+1)
  const int a = lane;
  const int fsw = 4 * ((a >> 2) & 3);          // = 4*((d>>3)&3) for d=2a,2a+1
  const int wslot = (2 * w) ^ fsw;
  const int wbase0 = (2 * a) * SP + wslot;
  const int wbase1 = (2 * a + 1) * SP + wslot;

  f32x4 acc[4][2] = {};
  f32x4 ak[4] = {};
  bf16x8 ones;
  { uint32_t* u = (uint32_t*)&ones; u[0] = u[1] = u[2] = u[3] = 0x3F803F80u; }

#define ISSUE(T)                                                \
  do {                                                          \
    _Pragma("unroll") for (int j = 0; j < 4; ++j) {             \
      size_t off = (size_t)((T) * 32 + 4 * w + j) * NHD + 2 * a;\
      kr[j] = *(const float2*)(gk + off);                       \
      vr[j] = *(const float2*)(gv + off);                       \
    }                                                           \
  } while (0)

  float2 kr[4], vr[4];
  ISSUE(0);

  for (int t = 0; t < steps; ++t) {
    // ---- pack (featmap K, fp32 rounding path unchanged) + LDS write ----
    {
      uint2 kd0, kd1, vd0, vd1;
      kd0.x = pack_bf(featmap(kr[0].x), featmap(kr[1].x));
      kd0.y = pack_bf(featmap(kr[2].x), featmap(kr[3].x));
      kd1.x = pack_bf(featmap(kr[0].y), featmap(kr[1].y));
      kd1.y = pack_bf(featmap(kr[2].y), featmap(kr[3].y));
      vd0.x = pack_bf(vr[0].x, vr[1].x);
      vd0.y = pack_bf(vr[2].x, vr[3].x);
      vd1.x = pack_bf(vr[0].y, vr[1].y);
      vd1.y = pack_bf(vr[2].y, vr[3].y);
      *(uint2*)&kls[wbase0] = kd0;
      *(uint2*)&kls[wbase1] = kd1;
      *(uint2*)&vls[wbase0] = vd0;
      *(uint2*)&vls[wbase1] = vd1;
    }
    BAR_LGKM();
    if (t + 1 < steps) ISSUE(t + 1);   // loads fly under MFMA + next barrier
    // ---- fragment reads (b128) + MFMA ----
    {
      bf16x8 af[4], bfr[2];
#pragma unroll
      for (int fr = 0; fr < 4; ++fr) {
        int d = wr * 64 + fr * 16 + lr;
        af[fr] = *(const bf16x8*)&kls[d * SP + ((4 * lg) ^ (4 * ((d >> 3) & 3)))];
      }
#pragma unroll
      for (int fc = 0; fc < 2; ++fc) {
        int v = wc * 32 + fc * 16 + lr;
        bfr[fc] = *(const bf16x8*)&vls[v * SP + ((4 * lg) ^ (4 * ((v >> 3) & 3)))];
      }
#pragma unroll
      for (int fr = 0; fr < 4; ++fr)
#pragma unroll
        for (int fc = 0; fc < 2; ++fc)
          acc[fr][fc] = __builtin_amdgcn_mfma_f32_16x16x32_bf16(af[fr], bfr[fc], acc[fr][fc], 0, 0, 0);
      if (wc == 0) {
#pragma unroll
        for (int fr = 0; fr < 4; ++fr)
          ak[fr] = __builtin_amdgcn_mfma_f32_16x16x32_bf16(af[fr], ones, ak[fr], 0, 0, 0);
      }
    }
    BAR_LGKM();
  }
#undef ISSUE

  // C/D: col(v)=lane&15, row(d)=(lane>>4)*4+j. bf16 partial, write-once.
  ushort_t* dst = kvpb + ((size_t)chunk * 32 + nh) * 16384;
#pragma unroll
  for (int fr = 0; fr < 4; ++fr)
#pragma unroll
    for (int fc = 0; fc < 2; ++fc) {
      int d0 = wr * 64 + fr * 16 + lg * 4;
      int v  = wc * 32 + fc * 16 + lr;
      *(uint2*)(dst + (size_t)v * 128 + d0) =
          make_uint2(pack_bf(acc[fr][fc][0], acc[fr][fc][1]),
                     pack_bf(acc[fr][fc][2], acc[fr][fc][3]));
    }
  if (wc == 0 && lr == 0) {
    float* ks = kspart + ((size_t)chunk * 32 + nh) * 128;
#pragma unroll
    for (int fr = 0; fr < 4; ++fr)
      *(float4*)(ks + wr * 64 + fr * 16 + lg * 4) =
          make_float4(ak[fr][0], ak[fr][1], ak[fr][2], ak[fr][3]);
  }
}

// ---------------- Phase 1c: merge bf16 partials ----------------
__global__ __launch_bounds__(256) void kv_merge(const ushort_t* __restrict__ kvpb,
                                                const float* __restrict__ kspart,
                                                ushort_t* __restrict__ kvb,
                                                float* __restrict__ ksumg,
                                                int CH) {
  const int nh = blockIdx.x, q = blockIdx.y, tid = threadIdx.x;
  const size_t off = (size_t)nh * 16384 + q * 4096;
#pragma unroll
  for (int i = 0; i < 4; ++i) {
    size_t idx = off + (size_t)(i * 256 + tid) * 4;
    f32x4 s = {};
    for (int c = 0; c < CH; ++c) {
      uint2 u = *(const uint2*)(kvpb + (size_t)c * 524288 + idx);
      s[0] += __uint_as_float(u.x << 16);
      s[1] += __uint_as_float(u.x & 0xFFFF0000u);
      s[2] += __uint_as_float(u.y << 16);
      s[3] += __uint_as_float(u.y & 0xFFFF0000u);
    }
    *(uint2*)(kvb + idx) = make_uint2(pack_bf(s[0], s[1]), pack_bf(s[2], s[3]));
  }
  if (q == 0 && tid < 128) {
    float s = 0.f;
    for (int c = 0; c < CH; ++c) s += kspart[((size_t)c * 32 + nh) * 128 + tid];
    ksumg[nh * 128 + tid] = s;
  }
}

// ---------------- Phase 2: LDS-staged Q + direct-global B ----------------
__global__ __launch_bounds__(256, 4) void attn_out(const float* __restrict__ q,
                                                   const ushort_t* __restrict__ kvb,
                                                   const float* __restrict__ ksumg,
                                                   const float* __restrict__ thrp,
                                                   float* __restrict__ out) {
  __shared__ __align__(16) uint32_t As[128 * 17 * 4];  // 34.8KB
  __shared__ float zrow[128];

  const int tid = threadIdx.x;
  const int mc = blockIdx.x, nh = blockIdx.y;
  const int n = nh >> 3, h = nh & 7;
  const size_t qoff = ((size_t)(n * LSEQ + mc * 128)) * NHD + h * 128;
  const float thr = thrp[0];

  const int c4 = tid & 31;
  const float4 kk = *(const float4*)(ksumg + nh * 128 + c4 * 4);

  // ---- stage Qf -> As (bf16) + fp32 score on the fly ----
#pragma unroll
  for (int it = 0; it < 16; ++it) {
    int rr = it * 8 + (tid >> 5);
    float4 qv = *(const float4*)(q + qoff + (size_t)rr * NHD + c4 * 4);
    float f0 = featmap(qv.x), f1 = featmap(qv.y), f2 = featmap(qv.z), f3 = featmap(qv.w);
    uint32_t* dst = &As[(rr * 17 + (c4 >> 1)) * 4 + (c4 & 1) * 2];
    dst[0] = pack_bf(f0, f1);
    dst[1] = pack_bf(f2, f3);
    float p = f0 * kk.x + f1 * kk.y + f2 * kk.z + f3 * kk.w;
    p += __shfl_xor(p, 1);  p += __shfl_xor(p, 2);  p += __shfl_xor(p, 4);
    p += __shfl_xor(p, 8);  p += __shfl_xor(p, 16);
    if (c4 == 0) {
      float sp = p > thr ? p : 0.f;
      zrow[rr] = 1.f / (sp + 1e-6f);
    }
  }
  __syncthreads();

  // ---- MFMA: A from LDS, B direct from kvb (L2-hot 32KB) ----
  const int lane = tid & 63;
  const int w = tid >> 6;
  const int lr = lane & 15, lg = lane >> 4;
  const ushort_t* kvp = kvb + (size_t)nh * 16384;   // [v][d] bf16

  f32x4 acc0[8] = {};
  f32x4 acc1[8] = {};
#pragma unroll
  for (int ks = 0; ks < 4; ++ks) {
    const int c8 = ks * 4 + lg;
    const int dof = ks * 32 + lg * 8;
    const int r0 = w * 32 + lr;
    bf16x8 a0 = *(const bf16x8*)&As[(r0 * 17 + c8) * 4];
    bf16x8 a1 = *(const bf16x8*)&As[((r0 + 16) * 17 + c8) * 4];
#pragma unroll
    for (int ct = 0; ct < 8; ++ct) {
      bf16x8 bb = *(const bf16x8*)(kvp + (size_t)((ct * 16 + lr) * 128) + dof);
      acc0[ct] = __builtin_amdgcn_mfma_f32_16x16x32_bf16(a0, bb, acc0[ct], 0, 0, 0);
      acc1[ct] = __builtin_amdgcn_mfma_f32_16x16x32_bf16(a1, bb, acc1[ct], 0, 0, 0);
    }
  }

  float z0[4], z1[4];
#pragma unroll
  for (int j = 0; j < 4; ++j) {
    z0[j] = zrow[w * 32 + lg * 4 + j];
    z1[j] = zrow[w * 32 + 16 + lg * 4 + j];
  }
  float* op = out + qoff;
#pragma unroll
  for (int ct = 0; ct < 8; ++ct)
#pragma unroll
    for (int jj = 0; jj < 4; ++jj) {
      int row = w * 32 + lg * 4 + jj;   // C/D: col=lane&15, row=(lane>>4)*4+jj
      op[(size_t)row * NHD + ct * 16 + lr]        = acc0[ct][jj] * z0[jj];
      op[(size_t)(row + 16) * NHD + ct * 16 + lr] = acc1[ct][jj] * z1[jj];
    }
}

extern "C" void kernel_launch(void* const* d_in, const int* in_sizes, int n_in,
                              void* d_out, int out_size, void* d_ws, size_t ws_size,
                              hipStream_t stream) {
  const float* queries   = (const float*)d_in[0];
  const float* keys      = (const float*)d_in[1];
  const float* values    = (const float*)d_in[2];
  const float* threshold = (const float*)d_in[3];
  float* out = (float*)d_out;

  // ws: kvpb CH*1MB bf16 | kspart CH*16KB | kvb 1MB | ksumg 16KB  (CH=32 -> ~34MB)
  int CH = 32;
  while (CH > 1 &&
         (size_t)CH * (524288 * 2 + 32 * 128 * 4) + (size_t)32 * 16384 * 2 + 32 * 128 * 4 > ws_size)
    CH >>= 1;
  ushort_t* kvpb = (ushort_t*)d_ws;
  float* kspart  = (float*)(kvpb + (size_t)CH * 524288);
  ushort_t* kvb  = (ushort_t*)(kspart + (size_t)CH * 32 * 128);
  float* ksumg   = (float*)(kvb + (size_t)32 * 16384);

  kv_direct<<<dim3(CH, 8, 4), 512, 0, stream>>>(keys, values, kvpb, kspart);
  kv_merge<<<dim3(32, 4), 256, 0, stream>>>(kvpb, kspart, kvb, ksumg, CH);
  attn_out<<<dim3(64, 32), 256, 0, stream>>>(queries, kvb, ksumg, threshold, out);
}

// Round 14
// 177.293 us; speedup vs baseline: 1.1299x; 1.1299x over previous
//
#include <hip/hip_runtime.h>
#include <stdint.h>

// DynamicSparseLinearAttention on MI355X.
// N=4, L=8192, H=8, D=V=128. Layout [n][l][h][d], row stride H*D = 1024 floats.
//
// Lessons: (R4) atomics write through L2 -> never. (R5) small grids starve the
// chip. (R6) per-lane strided 16B loads w/o staging thrash L2. (R8) scalar LDS
// transpose reads cap at 2.4TB/s -> stage transposed+bf16-packed, b128 frag
// reads. (R9-R13) occupancy/pipelining/barrier knobs all NULL. (R13 analysis)
// effective BW tracks BYTES PER VMEM INSTRUCTION across all 7 kernels:
// b32 gather 1.3 TB/s, float2 1.6-2.9, float4 3.8-4.4 -> per-CU in-flight
// request queue (~6 entries) x bytes/instr / latency is the real roofline.
// => kv_direct loads must be float4. s-pair words built via shfl_xor(32)
// partner exchange; av=0 lanes write slot 2w, av=1 slot 2w+1.
//
// 3 launches:
//  kv_direct: fused retile+GEMM. Grid (CH=16,8,4)=512 blocks x 512 thr (8 waves
//             = 2 wr(d64) x 4 wc(v32)). Per 32-s step: 4x float4 loads/thread,
//             featmap K (fp32), bf16 pack + shfl merge, LDS [d][s2^swz] (SP=20,
//             4x b32 writes, b128 frag reads), 1-step prefetch, lgkm-only
//             barriers. fp32 partials, write-once, no atomics. Ksum via
//             ones-MFMA on wc==0 waves.
//  kv_merge:  sum CH fp32 partials -> kvb bf16 [nh][v][d] + ksumg.
//  attn_out:  Q staged to LDS bf16 (row*17 padded chunks), score during staging
//             (fp32 + shfl_xor), B-frags direct from L2-hot kvb. One barrier.

#define LSEQ 8192
#define NHD  1024   // H*D
#define SP   20     // LDS dwords per d-row: 16 s-pair slots + 4 pad

typedef __attribute__((ext_vector_type(4))) float f32x4;
typedef __attribute__((ext_vector_type(8))) short bf16x8;
typedef unsigned short ushort_t;

static __device__ __forceinline__ unsigned short f2bf(float x) {
  union { float f; uint32_t u; } v; v.f = x;
  uint32_t r = v.u + 0x7FFFu + ((v.u >> 16) & 1u);  // RNE
  return (unsigned short)(r >> 16);
}
static __device__ __forceinline__ uint32_t pack_bf(float a, float b) {
  return (uint32_t)f2bf(a) | ((uint32_t)f2bf(b) << 16);
}
static __device__ __forceinline__ float featmap(float x) {
  // elu(x)+1 = x+1 (x>0) else exp(x)
  return x > 0.f ? x + 1.f : __expf(x);
}

// LDS-only barrier (ds ops drained; global loads stay in flight).
#define BAR_LGKM() asm volatile("s_waitcnt lgkmcnt(0)\n\ts_barrier" ::: "memory")

// ---------------- Phase 1: fused retile + KV GEMM, float4 loads -------------
// Grid (CH, 8 h, 4 n), 512 thr = 8 waves = 2 wr(d64) x 4 wc(v32).
// Loads: lane a, instr i: row 4w + (a>>5) + 2i, d-quad (a&31) -> 16B/lane.
// Stage: shfl_xor(32) pairs rows (4w,4w+1)->slot 2w (av=0 writes) and
// (4w+2,4w+3)->slot 2w+1 (av=1 writes); word(d,s2) = bf(s=2*s2)|bf(s=2*s2+1)<<16
// at dword [d*SP + (s2 ^ 4*((d>>3)&3))] -- identical layout to R10's.
__global__ __launch_bounds__(512, 4) void kv_direct(const float* __restrict__ keys,
                                                    const float* __restrict__ values,
                                                    float* __restrict__ kvp,
                                                    float* __restrict__ kspart) {
  __shared__ uint32_t kls[128 * SP];
  __shared__ uint32_t vls[128 * SP];
  const int tid = threadIdx.x;
  const int chunk = blockIdx.x, CH = gridDim.x;
  const int h = blockIdx.y, n = blockIdx.z, nh = n * 8 + h;
  const int lane = tid & 63, w = tid >> 6;
  const int wr = w >> 2, wc = w & 3;
  const int lr = lane & 15, lg = lane >> 4;
  const int sPer = LSEQ / CH;        // 512 at CH=16
  const int steps = sPer / 32;       // 16 at CH=16

  const size_t gb = ((size_t)n * LSEQ + (size_t)chunk * sPer) * NHD + h * 128;
  const float* gk = keys + gb;
  const float* gv = values + gb;

  const int av = lane >> 5;          // row-half within the wave's 4 rows
  const int q  = lane & 31;          // d-quad: d = 4q..4q+3
  const int swzq = 4 * ((q >> 1) & 3);              // = 4*((d>>3)&3), same for quad
  const int base0 = (4 * q) * SP + ((2 * w + av) ^ swzq);

  f32x4 acc[4][2] = {};
  f32x4 ak[4] = {};
  bf16x8 ones;
  { uint32_t* u = (uint32_t*)&ones; u[0] = u[1] = u[2] = u[3] = 0x3F803F80u; }

#define ISSUE(T)                                                     \
  do {                                                               \
    _Pragma("unroll") for (int i = 0; i < 2; ++i) {                  \
      size_t off = (size_t)((T) * 32 + 4 * w + av + 2 * i) * NHD + 4 * q; \
      kr4[i] = *(const float4*)(gk + off);                           \
      vr4[i] = *(const float4*)(gv + off);                           \
    }                                                                \
  } while (0)

  float4 kr4[2], vr4[2];
  ISSUE(0);

  for (int t = 0; t < steps; ++t) {
    // ---- pack + shfl merge + LDS write ----
    {
      // K (featmap in fp32 -- same rounding path as all prior rounds)
      uint2 u0, u1, p0, p1, lo, hi;
      u0.x = pack_bf(featmap(kr4[0].x), featmap(kr4[0].y));
      u0.y = pack_bf(featmap(kr4[0].z), featmap(kr4[0].w));
      u1.x = pack_bf(featmap(kr4[1].x), featmap(kr4[1].y));
      u1.y = pack_bf(featmap(kr4[1].z), featmap(kr4[1].w));
      p0.x = __shfl_xor((int)u0.x, 32); p0.y = __shfl_xor((int)u0.y, 32);
      p1.x = __shfl_xor((int)u1.x, 32); p1.y = __shfl_xor((int)u1.y, 32);
      lo.x = av ? p1.x : u0.x;  lo.y = av ? p1.y : u0.y;
      hi.x = av ? u1.x : p0.x;  hi.y = av ? u1.y : p0.y;
      kls[base0]          = (lo.x & 0xFFFFu) | (hi.x << 16);
      kls[base0 + SP]     = (lo.x >> 16) | (hi.x & 0xFFFF0000u);
      kls[base0 + 2 * SP] = (lo.y & 0xFFFFu) | (hi.y << 16);
      kls[base0 + 3 * SP] = (lo.y >> 16) | (hi.y & 0xFFFF0000u);
      // V (raw)
      u0.x = pack_bf(vr4[0].x, vr4[0].y);
      u0.y = pack_bf(vr4[0].z, vr4[0].w);
      u1.x = pack_bf(vr4[1].x, vr4[1].y);
      u1.y = pack_bf(vr4[1].z, vr4[1].w);
      p0.x = __shfl_xor((int)u0.x, 32); p0.y = __shfl_xor((int)u0.y, 32);
      p1.x = __shfl_xor((int)u1.x, 32); p1.y = __shfl_xor((int)u1.y, 32);
      lo.x = av ? p1.x : u0.x;  lo.y = av ? p1.y : u0.y;
      hi.x = av ? u1.x : p0.x;  hi.y = av ? u1.y : p0.y;
      vls[base0]          = (lo.x & 0xFFFFu) | (hi.x << 16);
      vls[base0 + SP]     = (lo.x >> 16) | (hi.x & 0xFFFF0000u);
      vls[base0 + 2 * SP] = (lo.y & 0xFFFFu) | (hi.y << 16);
      vls[base0 + 3 * SP] = (lo.y >> 16) | (hi.y & 0xFFFF0000u);
    }
    BAR_LGKM();
    if (t + 1 < steps) ISSUE(t + 1);   // float4 loads fly under MFMA + barrier
    // ---- fragment reads (b128) + MFMA ----
    {
      bf16x8 af[4], bfr[2];
#pragma unroll
      for (int fr = 0; fr < 4; ++fr) {
        int d = wr * 64 + fr * 16 + lr;
        af[fr] = *(const bf16x8*)&kls[d * SP + ((4 * lg) ^ (4 * ((d >> 3) & 3)))];
      }
#pragma unroll
      for (int fc = 0; fc < 2; ++fc) {
        int v = wc * 32 + fc * 16 + lr;
        bfr[fc] = *(const bf16x8*)&vls[v * SP + ((4 * lg) ^ (4 * ((v >> 3) & 3)))];
      }
#pragma unroll
      for (int fr = 0; fr < 4; ++fr)
#pragma unroll
        for (int fc = 0; fc < 2; ++fc)
          acc[fr][fc] = __builtin_amdgcn_mfma_f32_16x16x32_bf16(af[fr], bfr[fc], acc[fr][fc], 0, 0, 0);
      if (wc == 0) {
#pragma unroll
        for (int fr = 0; fr < 4; ++fr)
          ak[fr] = __builtin_amdgcn_mfma_f32_16x16x32_bf16(af[fr], ones, ak[fr], 0, 0, 0);
      }
    }
    BAR_LGKM();
  }
#undef ISSUE

  // C/D: col(v)=lane&15, row(d)=(lane>>4)*4+j. fp32 partial, write-once.
  float* dst = kvp + ((size_t)chunk * 32 + nh) * 16384;
#pragma unroll
  for (int fr = 0; fr < 4; ++fr)
#pragma unroll
    for (int fc = 0; fc < 2; ++fc) {
      int d0 = wr * 64 + fr * 16 + lg * 4;
      int v  = wc * 32 + fc * 16 + lr;
      *(float4*)(dst + (size_t)v * 128 + d0) =
          make_float4(acc[fr][fc][0], acc[fr][fc][1], acc[fr][fc][2], acc[fr][fc][3]);
    }
  if (wc == 0 && lr == 0) {
    float* ks = kspart + ((size_t)chunk * 32 + nh) * 128;
#pragma unroll
    for (int fr = 0; fr < 4; ++fr)
      *(float4*)(ks + wr * 64 + fr * 16 + lg * 4) =
          make_float4(ak[fr][0], ak[fr][1], ak[fr][2], ak[fr][3]);
  }
}

// ---------------- Phase 1c: merge fp32 partials ----------------
__global__ __launch_bounds__(256) void kv_merge(const float* __restrict__ kvp,
                                                const float* __restrict__ kspart,
                                                ushort_t* __restrict__ kvb,
                                                float* __restrict__ ksumg,
                                                int CH) {
  const int nh = blockIdx.x, q = blockIdx.y, tid = threadIdx.x;
  const size_t off = (size_t)nh * 16384 + q * 4096;
#pragma unroll
  for (int i = 0; i < 4; ++i) {
    size_t idx = off + (size_t)(i * 256 + tid) * 4;
    f32x4 s = {};
    for (int c = 0; c < CH; ++c)
      s += *(const f32x4*)(kvp + (size_t)c * 524288 + idx);
    *(uint2*)(kvb + idx) = make_uint2(pack_bf(s[0], s[1]), pack_bf(s[2], s[3]));
  }
  if (q == 0 && tid < 128) {
    float s = 0.f;
    for (int c = 0; c < CH; ++c) s += kspart[((size_t)c * 32 + nh) * 128 + tid];
    ksumg[nh * 128 + tid] = s;
  }
}

// ---------------- Phase 2: LDS-staged Q + direct-global B ----------------
__global__ __launch_bounds__(256, 4) void attn_out(const float* __restrict__ q,
                                                   const ushort_t* __restrict__ kvb,
                                                   const float* __restrict__ ksumg,
                                                   const float* __restrict__ thrp,
                                                   float* __restrict__ out) {
  __shared__ __align__(16) uint32_t As[128 * 17 * 4];  // 34.8KB
  __shared__ float zrow[128];

  const int tid = threadIdx.x;
  const int mc = blockIdx.x, nh = blockIdx.y;
  const int n = nh >> 3, h = nh & 7;
  const size_t qoff = ((size_t)(n * LSEQ + mc * 128)) * NHD + h * 128;
  const float thr = thrp[0];

  const int c4 = tid & 31;
  const float4 kk = *(const float4*)(ksumg + nh * 128 + c4 * 4);

  // ---- stage Qf -> As (bf16) + fp32 score on the fly ----
#pragma unroll
  for (int it = 0; it < 16; ++it) {
    int rr = it * 8 + (tid >> 5);
    float4 qv = *(const float4*)(q + qoff + (size_t)rr * NHD + c4 * 4);
    float f0 = featmap(qv.x), f1 = featmap(qv.y), f2 = featmap(qv.z), f3 = featmap(qv.w);
    uint32_t* dst = &As[(rr * 17 + (c4 >> 1)) * 4 + (c4 & 1) * 2];
    dst[0] = pack_bf(f0, f1);
    dst[1] = pack_bf(f2, f3);
    float p = f0 * kk.x + f1 * kk.y + f2 * kk.z + f3 * kk.w;
    p += __shfl_xor(p, 1);  p += __shfl_xor(p, 2);  p += __shfl_xor(p, 4);
    p += __shfl_xor(p, 8);  p += __shfl_xor(p, 16);
    if (c4 == 0) {
      float sp = p > thr ? p : 0.f;
      zrow[rr] = 1.f / (sp + 1e-6f);
    }
  }
  __syncthreads();

  // ---- MFMA: A from LDS, B direct from kvb (L2-hot 32KB) ----
  const int lane = tid & 63;
  const int w = tid >> 6;
  const int lr = lane & 15, lg = lane >> 4;
  const ushort_t* kvp = kvb + (size_t)nh * 16384;   // [v][d] bf16

  f32x4 acc0[8] = {};
  f32x4 acc1[8] = {};
#pragma unroll
  for (int ks = 0; ks < 4; ++ks) {
    const int c8 = ks * 4 + lg;
    const int dof = ks * 32 + lg * 8;
    const int r0 = w * 32 + lr;
    bf16x8 a0 = *(const bf16x8*)&As[(r0 * 17 + c8) * 4];
    bf16x8 a1 = *(const bf16x8*)&As[((r0 + 16) * 17 + c8) * 4];
#pragma unroll
    for (int ct = 0; ct < 8; ++ct) {
      bf16x8 bb = *(const bf16x8*)(kvp + (size_t)((ct * 16 + lr) * 128) + dof);
      acc0[ct] = __builtin_amdgcn_mfma_f32_16x16x32_bf16(a0, bb, acc0[ct], 0, 0, 0);
      acc1[ct] = __builtin_amdgcn_mfma_f32_16x16x32_bf16(a1, bb, acc1[ct], 0, 0, 0);
    }
  }

  float z0[4], z1[4];
#pragma unroll
  for (int j = 0; j < 4; ++j) {
    z0[j] = zrow[w * 32 + lg * 4 + j];
    z1[j] = zrow[w * 32 + 16 + lg * 4 + j];
  }
  float* op = out + qoff;
#pragma unroll
  for (int ct = 0; ct < 8; ++ct)
#pragma unroll
    for (int jj = 0; jj < 4; ++jj) {
      int row = w * 32 + lg * 4 + jj;   // C/D: col=lane&15, row=(lane>>4)*4+jj
      op[(size_t)row * NHD + ct * 16 + lr]        = acc0[ct][jj] * z0[jj];
      op[(size_t)(row + 16) * NHD + ct * 16 + lr] = acc1[ct][jj] * z1[jj];
    }
}

extern "C" void kernel_launch(void* const* d_in, const int* in_sizes, int n_in,
                              void* d_out, int out_size, void* d_ws, size_t ws_size,
                              hipStream_t stream) {
  const float* queries   = (const float*)d_in[0];
  const float* keys      = (const float*)d_in[1];
  const float* values    = (const float*)d_in[2];
  const float* threshold = (const float*)d_in[3];
  float* out = (float*)d_out;

  // ws: kvp CH*2MB fp32 | kspart CH*16KB | kvb 1MB | ksumg 16KB (CH=16 ~34.9MB)
  int CH = 16;
  while (CH > 1 &&
         (size_t)CH * (524288 + 32 * 128) * 4 + (size_t)32 * 16384 * 2 + 32 * 128 * 4 > ws_size)
    CH >>= 1;
  float* kvp     = (float*)d_ws;
  float* kspart  = kvp + (size_t)CH * 524288;
  ushort_t* kvb  = (ushort_t*)(kspart + (size_t)CH * 32 * 128);
  float* ksumg   = (float*)(kvb + (size_t)32 * 16384);

  kv_direct<<<dim3(CH, 8, 4), 512, 0, stream>>>(keys, values, kvp, kspart);
  kv_merge<<<dim3(32, 4), 256, 0, stream>>>(kvp, kspart, kvb, ksumg, CH);
  attn_out<<<dim3(64, 32), 256, 0, stream>>>(queries, kvb, ksumg, threshold, out);
}